// Round 9
// baseline (630.048 us; speedup 1.0000x reference)
//
#include <hip/hip_runtime.h>

#define N_IMG_D 150528   // 3*224*224
#define CH_STRIDE 50176  // 224*224

// ---------------------------------------------------------------------------
// Fully fused ViT forward: one block per image, 576 threads.
//  E:  patch embed. Threads 0..511 = 8 waves; waves 0-3 K-half 0 (flat 0..20),
//      waves 4-7 K-half 1 (flat 21..41). Wave-uniform Wm row pointer -> weight
//      reads are scalar (s_load) broadcasts, no LDS staging. Lane owns one
//      patch. half1 stores partials to red2; half0 combines after the barrier
//      and writes tokens straight into xb (no global round-trip, no xws).
//  P1: LN1 + Q/K/V both heads fused (257 threads), q pre-scaled by SC.
//  P2: attention, 4 queries/thread -> 2 heavy waves + cls pair (k/v reads are
//      uniform-address LDS broadcasts; VALU-bound).
//  P3: LN2.  P4: MLP (exact-erf GELU).  Head: out = x[0] @ Wf + bf.
// ---------------------------------------------------------------------------
__global__ __launch_bounds__(576) void k_vit_fused(
    const float* __restrict__ img, const int* __restrict__ labels,
    const float* __restrict__ Wm, const float* __restrict__ bm,
    const float* __restrict__ cls_table, const float* __restrict__ pe,
    const float* __restrict__ ln1_g, const float* __restrict__ ln1_b,
    const float* __restrict__ Wq, const float* __restrict__ bq,
    const float* __restrict__ Wk, const float* __restrict__ bk,
    const float* __restrict__ Wv, const float* __restrict__ bv,
    const float* __restrict__ ln2_g, const float* __restrict__ ln2_b,
    const float* __restrict__ W1, const float* __restrict__ b1,
    const float* __restrict__ W2, const float* __restrict__ b2,
    const float* __restrict__ Wf, const float* __restrict__ bf,
    float* __restrict__ out)
{
    __shared__ __align__(16) float xb[257 * 9];       // x, row-padded to 9
    __shared__ __align__(16) float hb[257 * 9];       // LN2 output
    __shared__ __align__(16) float qb[2 * 257 * 4];   // q (pre-scaled), float4 rows
    __shared__ __align__(16) float kb[2 * 257 * 4];   // k
    __shared__ __align__(16) float vb[2 * 257 * 4];   // v
    __shared__ float red2[256 * 9];                   // half1 embed partials, stride 9
    __shared__ float wqs[64], wks[64], wvs[64];
    __shared__ float bqs[16], bks[16], bvs[16];
    __shared__ float w1s[512], b1s[64], w2s[512], b2s[16];

    const int t = threadIdx.x;
    const int n = blockIdx.x;

    // Stage small weights once (L2-hot, trivial).
    for (int i = t; i < 64; i += 576) { wqs[i] = Wq[i]; wks[i] = Wk[i]; wvs[i] = Wv[i]; b1s[i] = b1[i]; }
    for (int i = t; i < 16; i += 576) { bqs[i] = bq[i]; bks[i] = bk[i]; bvs[i] = bv[i]; b2s[i] = b2[i]; }
    for (int i = t; i < 512; i += 576) { w1s[i] = W1[i]; w2s[i] = W2[i]; }

    // ---- E: patch embed, K-range split across wave halves ----
    const bool emb = (t < 512);
    int half = 0, p = 0;
    float acc[8] = {0.f, 0.f, 0.f, 0.f, 0.f, 0.f, 0.f, 0.f};
    if (emb) {
        half = __builtin_amdgcn_readfirstlane(t >> 8);   // wave-uniform 0/1
        p = t & 255;                                     // patch 0..255
        const int py = p >> 4, px = p & 15;
        int c = half;                  // half0: (c,r)=(0,0) flat 0..20
        int r = half * 7;              // half1: (c,r)=(1,7) flat 21..41
        const float* ib = img + (size_t)n * N_IMG_D + c * CH_STRIDE + (py * 14 + r) * 224 + px * 14;
        const float* wrow = Wm + (c * 196 + r * 14) * 8;   // wave-uniform pointer
        for (int it = 0; it < 21; ++it) {
            #pragma unroll 7
            for (int col = 0; col < 14; ++col) {
                const float v = ib[col];
                const float* w = wrow + col * 8;           // uniform -> scalar loads
                #pragma unroll
                for (int e = 0; e < 8; ++e) acc[e] += v * w[e];
            }
            ++r; ib += 224; wrow += 112;
            if (r == 14) { r = 0; ++c; ib += CH_STRIDE - 14 * 224; }  // uniform branch
        }
        if (half) {
            #pragma unroll
            for (int e = 0; e < 8; ++e) red2[p * 9 + e] = acc[e];    // half1 only
        }
    } else if (t < 520) {              // cls row 0
        const int e = t - 512;
        xb[e] = cls_table[labels[n] * 8 + e] + pe[e];
    }
    __syncthreads();
    if (emb && half == 0) {
        const float* pr = pe + (p + 1) * 8;
        #pragma unroll
        for (int e = 0; e < 8; ++e)
            xb[(p + 1) * 9 + e] = acc[e] + red2[p * 9 + e] + bm[e] + pr[e];
    }
    __syncthreads();

    const float SC = 0.72134752044f;   // (1/sqrt(DH)=0.5) * log2(e)

    for (int l = 0; l < 2; ++l) {
        // ---- P1: LN1 + Q,K,V for both heads ----
        if (t < 257) {
            float v0[8]; float m = 0.f;
            #pragma unroll
            for (int e = 0; e < 8; ++e) { v0[e] = xb[t * 9 + e]; m += v0[e]; }
            m *= 0.125f;
            float var = 0.f;
            #pragma unroll
            for (int e = 0; e < 8; ++e) { float d = v0[e] - m; var += d * d; }
            var *= 0.125f;
            const float rs = rsqrtf(var + 1e-5f);
            const float* g = ln1_g + l * 8; const float* bb = ln1_b + l * 8;
            float ln[8];
            #pragma unroll
            for (int e = 0; e < 8; ++e) ln[e] = (v0[e] - m) * rs * g[e] + bb[e];

            #pragma unroll
            for (int h = 0; h < 2; ++h) {
                const int wb_ = (l * 2 + h);
                const float* wq = wqs + wb_ * 16; const float* bq_ = bqs + wb_ * 4;
                const float* wk = wks + wb_ * 16; const float* bk_ = bks + wb_ * 4;
                const float* wv = wvs + wb_ * 16; const float* bv_ = bvs + wb_ * 4;
                float qq[4], kk[4], vv[4];
                #pragma unroll
                for (int e = 0; e < 4; ++e) { qq[e] = bq_[e]; kk[e] = bk_[e]; vv[e] = bv_[e]; }
                #pragma unroll
                for (int d = 0; d < 4; ++d) {
                    const float hd = ln[h * 4 + d];
                    #pragma unroll
                    for (int e = 0; e < 4; ++e) {
                        qq[e] += hd * wq[d * 4 + e];
                        kk[e] += hd * wk[d * 4 + e];
                        vv[e] += hd * wv[d * 4 + e];
                    }
                }
                const int ri = (h * 257 + t) * 4;
                *reinterpret_cast<float4*>(qb + ri) =
                    make_float4(qq[0] * SC, qq[1] * SC, qq[2] * SC, qq[3] * SC);
                *reinterpret_cast<float4*>(kb + ri) = make_float4(kk[0], kk[1], kk[2], kk[3]);
                *reinterpret_cast<float4*>(vb + ri) = make_float4(vv[0], vv[1], vv[2], vv[3]);
            }
        }
        __syncthreads();

        // ---- P2: attention, 4 queries/thread (2 heavy waves) + cls pair ----
        if (t < 130) {
            if (t < 128) {
                const int h  = t >> 6;
                const int j0 = t & 63;
                const float4* qp = reinterpret_cast<const float4*>(qb) + h * 257;
                const float4* kp = reinterpret_cast<const float4*>(kb) + h * 257;
                const float4* vp = reinterpret_cast<const float4*>(vb) + h * 257;
                const float4 q0 = qp[j0], q1 = qp[j0 + 64], q2 = qp[j0 + 128], q3 = qp[j0 + 192];
                float l0 = 0.f, l1 = 0.f, l2 = 0.f, l3 = 0.f;
                float4 o0 = {0,0,0,0}, o1 = {0,0,0,0}, o2 = {0,0,0,0}, o3 = {0,0,0,0};
                #pragma unroll 2
                for (int tt = 0; tt < 257; ++tt) {
                    const float4 kk = kp[tt];
                    const float4 vv = vp[tt];
                    const float d0 = q0.x*kk.x + q0.y*kk.y + q0.z*kk.z + q0.w*kk.w;
                    const float d1 = q1.x*kk.x + q1.y*kk.y + q1.z*kk.z + q1.w*kk.w;
                    const float d2 = q2.x*kk.x + q2.y*kk.y + q2.z*kk.z + q2.w*kk.w;
                    const float d3 = q3.x*kk.x + q3.y*kk.y + q3.z*kk.z + q3.w*kk.w;
                    const float p0 = exp2f(d0), p1 = exp2f(d1), p2 = exp2f(d2), p3 = exp2f(d3);
                    l0 += p0; l1 += p1; l2 += p2; l3 += p3;
                    o0.x += p0*vv.x; o0.y += p0*vv.y; o0.z += p0*vv.z; o0.w += p0*vv.w;
                    o1.x += p1*vv.x; o1.y += p1*vv.y; o1.z += p1*vv.z; o1.w += p1*vv.w;
                    o2.x += p2*vv.x; o2.y += p2*vv.y; o2.z += p2*vv.z; o2.w += p2*vv.w;
                    o3.x += p3*vv.x; o3.y += p3*vv.y; o3.z += p3*vv.z; o3.w += p3*vv.w;
                }
                {
                    const float i0 = 1.0f / l0; float* xr = xb + (j0      ) * 9 + h * 4;
                    xr[0] += o0.x*i0; xr[1] += o0.y*i0; xr[2] += o0.z*i0; xr[3] += o0.w*i0;
                }
                {
                    const float i1 = 1.0f / l1; float* xr = xb + (j0 +  64) * 9 + h * 4;
                    xr[0] += o1.x*i1; xr[1] += o1.y*i1; xr[2] += o1.z*i1; xr[3] += o1.w*i1;
                }
                {
                    const float i2 = 1.0f / l2; float* xr = xb + (j0 + 128) * 9 + h * 4;
                    xr[0] += o2.x*i2; xr[1] += o2.y*i2; xr[2] += o2.z*i2; xr[3] += o2.w*i2;
                }
                {
                    const float i3 = 1.0f / l3; float* xr = xb + (j0 + 192) * 9 + h * 4;
                    xr[0] += o3.x*i3; xr[1] += o3.y*i3; xr[2] += o3.z*i3; xr[3] += o3.w*i3;
                }
            } else {
                const int h = t - 128;                 // query 256 (cls) per head
                const float4* qp = reinterpret_cast<const float4*>(qb) + h * 257;
                const float4* kp = reinterpret_cast<const float4*>(kb) + h * 257;
                const float4* vp = reinterpret_cast<const float4*>(vb) + h * 257;
                const float4 q0 = qp[256];
                float l0 = 0.f; float4 o0 = {0,0,0,0};
                #pragma unroll 2
                for (int tt = 0; tt < 257; ++tt) {
                    const float4 kk = kp[tt];
                    const float4 vv = vp[tt];
                    const float d0 = q0.x*kk.x + q0.y*kk.y + q0.z*kk.z + q0.w*kk.w;
                    const float p0 = exp2f(d0);
                    l0 += p0;
                    o0.x += p0*vv.x; o0.y += p0*vv.y; o0.z += p0*vv.z; o0.w += p0*vv.w;
                }
                const float i0 = 1.0f / l0; float* xr = xb + 256 * 9 + h * 4;
                xr[0] += o0.x*i0; xr[1] += o0.y*i0; xr[2] += o0.z*i0; xr[3] += o0.w*i0;
            }
        }
        __syncthreads();

        // ---- P3: LN2 ----
        if (t < 257) {
            float v0[8]; float m = 0.f;
            #pragma unroll
            for (int e = 0; e < 8; ++e) { v0[e] = xb[t * 9 + e]; m += v0[e]; }
            m *= 0.125f;
            float var = 0.f;
            #pragma unroll
            for (int e = 0; e < 8; ++e) { float d = v0[e] - m; var += d * d; }
            var *= 0.125f;
            const float rs = rsqrtf(var + 1e-5f);
            const float* g = ln2_g + l * 8; const float* bb = ln2_b + l * 8;
            #pragma unroll
            for (int e = 0; e < 8; ++e) hb[t * 9 + e] = (v0[e] - m) * rs * g[e] + bb[e];
        }
        __syncthreads();

        // ---- P4: MLP (exact-erf GELU) ----
        if (t < 257) {
            float hv[8];
            #pragma unroll
            for (int e = 0; e < 8; ++e) hv[e] = hb[t * 9 + e];
            float a8[8] = {0.f, 0.f, 0.f, 0.f, 0.f, 0.f, 0.f, 0.f};
            const float* w1 = w1s + l * 256; const float* bb1 = b1s + l * 32;
            const float* w2 = w2s + l * 256; const float* bb2 = b2s + l * 8;
            for (int u = 0; u < 32; ++u) {
                float a = bb1[u];
                #pragma unroll
                for (int e = 0; e < 8; ++e) a += hv[e] * w1[e * 32 + u];
                const float gl = 0.5f * a * (1.0f + erff(a * 0.70710678f));
                #pragma unroll
                for (int e = 0; e < 8; ++e) a8[e] += gl * w2[u * 8 + e];
            }
            #pragma unroll
            for (int e = 0; e < 8; ++e) xb[t * 9 + e] += a8[e] + bb2[e];
        }
        __syncthreads();
    }

    // ---- Head: out = x[0] @ Wf + bf ----
    if (t < 10) {
        float a = bf[t];
        #pragma unroll
        for (int e = 0; e < 8; ++e) a += xb[e] * Wf[e * 10 + t];
        out[(size_t)n * 10 + t] = a;
    }
}

extern "C" void kernel_launch(void* const* d_in, const int* in_sizes, int n_in,
                              void* d_out, int out_size, void* d_ws, size_t ws_size,
                              hipStream_t stream) {
    const float* img    = (const float*)d_in[0];
    const int*   labels = (const int*)  d_in[1];
    const float* Wm     = (const float*)d_in[2];
    const float* bm     = (const float*)d_in[3];
    const float* cls    = (const float*)d_in[4];
    const float* pe     = (const float*)d_in[5];
    const float* ln1_g  = (const float*)d_in[6];
    const float* ln1_b  = (const float*)d_in[7];
    const float* Wq     = (const float*)d_in[8];
    const float* bq     = (const float*)d_in[9];
    const float* Wk     = (const float*)d_in[10];
    const float* bk     = (const float*)d_in[11];
    const float* Wv     = (const float*)d_in[12];
    const float* bv     = (const float*)d_in[13];
    const float* ln2_g  = (const float*)d_in[14];
    const float* ln2_b  = (const float*)d_in[15];
    const float* W1     = (const float*)d_in[16];
    const float* b1     = (const float*)d_in[17];
    const float* W2     = (const float*)d_in[18];
    const float* b2     = (const float*)d_in[19];
    const float* Wf     = (const float*)d_in[20];
    const float* bf     = (const float*)d_in[21];
    float* out = (float*)d_out;

    const int n = in_sizes[0] / N_IMG_D;           // 512 images
    k_vit_fused<<<n, 576, 0, stream>>>(img, labels, Wm, bm, cls, pe,
        ln1_g, ln1_b, Wq, bq, Wk, bk, Wv, bv, ln2_g, ln2_b,
        W1, b1, W2, b2, Wf, bf, out);
}

// Round 10
// 572.190 us; speedup vs baseline: 1.1011x; 1.1011x over previous
//
#include <hip/hip_runtime.h>

#define N_IMG_D 150528   // 3*224*224
#define CH_STRIDE 50176  // 224*224

// ---------------------------------------------------------------------------
// Kernel 1 (v7): patchify + linear embed + positional embedding.
// grid = n_images*16 (block per image per patch-row py), block = 256.
// Thread (s, pg4, j): k-eighth stream s (flat = 8*it+s), 4 patches
// {pg4, pg4+4, pg4+8, pg4+12}, col-pair j. The 4 weight ds_read_b128 per
// iter are register-reused across 4 patches -> DS instrs cut 4x vs round-5.
// ---------------------------------------------------------------------------
__global__ __launch_bounds__(256) void k_patch_embed(
    const float* __restrict__ img, const float* __restrict__ Wm,
    const float* __restrict__ bm, const float* __restrict__ pe,
    float* __restrict__ xws)
{
    __shared__ __align__(16) float wmA[588 * 4];   // Wm[k][0..3]
    __shared__ __align__(16) float wmB[588 * 4];   // Wm[k][4..7]
    __shared__ float red[224 * 33];                // 4 patches x 8 e, stride 33

    const int t = threadIdx.x;
    const int b = blockIdx.x;
    const int n = b >> 4, py = b & 15;

    // Stage Wm into two LDS planes (even float4 -> wmA = e0..3, odd -> wmB).
    for (int i = t; i < 1176; i += 256) {           // 1176 float4 = 588*8 floats
        float4 w = reinterpret_cast<const float4*>(Wm)[i];
        float* dst = (i & 1) ? wmB : wmA;
        *reinterpret_cast<float4*>(dst + (i >> 1) * 4) = w;
    }
    __syncthreads();

    if (t < 224) {
        const int s   = t / 28;           // k-eighth stream 0..7
        const int t1  = t - s * 28;
        const int pg4 = t1 / 7;           // patch group 0..3
        const int j   = t1 - pg4 * 7;     // col pair 0..6
        const int col0 = 2 * j;
        // flat = 8*it + s walks s, s+8, ..., <= 41 ; flat = c*14 + r.
        int c = 0, r = s;
        const float* ib = img + (size_t)n * N_IMG_D + (py * 14 + r) * 224 + pg4 * 14 + col0;
        const float* wA = wmA + (s * 14 + col0) * 4;   // k = flat*14 + col0
        const float* wB = wmB + (s * 14 + col0) * 4;
        float a[32];
        #pragma unroll
        for (int i = 0; i < 32; ++i) a[i] = 0.f;
        const int iters = (s < 2) ? 6 : 5;            // flat<=41
        for (int it = 0; it < iters; ++it) {
            const float2 v0 = *reinterpret_cast<const float2*>(ib);         // patch pg4
            const float2 v1 = *reinterpret_cast<const float2*>(ib + 56);    // +4
            const float2 v2 = *reinterpret_cast<const float2*>(ib + 112);   // +8
            const float2 v3 = *reinterpret_cast<const float2*>(ib + 168);   // +12
            const float4 wa0 = *reinterpret_cast<const float4*>(wA);        // row k,  e0..3
            const float4 wa1 = *reinterpret_cast<const float4*>(wA + 4);    // row k+1,e0..3
            const float4 wb0 = *reinterpret_cast<const float4*>(wB);        // row k,  e4..7
            const float4 wb1 = *reinterpret_cast<const float4*>(wB + 4);    // row k+1,e4..7
            a[0]  += v0.x*wa0.x + v0.y*wa1.x;  a[1]  += v0.x*wa0.y + v0.y*wa1.y;
            a[2]  += v0.x*wa0.z + v0.y*wa1.z;  a[3]  += v0.x*wa0.w + v0.y*wa1.w;
            a[4]  += v0.x*wb0.x + v0.y*wb1.x;  a[5]  += v0.x*wb0.y + v0.y*wb1.y;
            a[6]  += v0.x*wb0.z + v0.y*wb1.z;  a[7]  += v0.x*wb0.w + v0.y*wb1.w;
            a[8]  += v1.x*wa0.x + v1.y*wa1.x;  a[9]  += v1.x*wa0.y + v1.y*wa1.y;
            a[10] += v1.x*wa0.z + v1.y*wa1.z;  a[11] += v1.x*wa0.w + v1.y*wa1.w;
            a[12] += v1.x*wb0.x + v1.y*wb1.x;  a[13] += v1.x*wb0.y + v1.y*wb1.y;
            a[14] += v1.x*wb0.z + v1.y*wb1.z;  a[15] += v1.x*wb0.w + v1.y*wb1.w;
            a[16] += v2.x*wa0.x + v2.y*wa1.x;  a[17] += v2.x*wa0.y + v2.y*wa1.y;
            a[18] += v2.x*wa0.z + v2.y*wa1.z;  a[19] += v2.x*wa0.w + v2.y*wa1.w;
            a[20] += v2.x*wb0.x + v2.y*wb1.x;  a[21] += v2.x*wb0.y + v2.y*wb1.y;
            a[22] += v2.x*wb0.z + v2.y*wb1.z;  a[23] += v2.x*wb0.w + v2.y*wb1.w;
            a[24] += v3.x*wa0.x + v3.y*wa1.x;  a[25] += v3.x*wa0.y + v3.y*wa1.y;
            a[26] += v3.x*wa0.z + v3.y*wa1.z;  a[27] += v3.x*wa0.w + v3.y*wa1.w;
            a[28] += v3.x*wb0.x + v3.y*wb1.x;  a[29] += v3.x*wb0.y + v3.y*wb1.y;
            a[30] += v3.x*wb0.z + v3.y*wb1.z;  a[31] += v3.x*wb0.w + v3.y*wb1.w;
            // advance flat by 8: r += 8 (wrap), k += 112 -> +448 words
            r += 8; ib += 8 * 224; wA += 448; wB += 448;
            if (r >= 14) { r -= 14; ++c; ib += CH_STRIDE - 14 * 224; }
        }
        float* rd = red + t * 33;          // stride 33 (odd): conflict-free b32
        #pragma unroll
        for (int i = 0; i < 32; ++i) rd[i] = a[i];
    }
    __syncthreads();

    if (t < 128) {                        // 16 patches x 8 outputs
        const int p = t >> 3, e = t & 7;
        const int pg4 = p & 3, sub = p >> 2;
        float sum = 0.f;
        #pragma unroll
        for (int q = 0; q < 56; ++q) {    // q = s*7 + j
            const int s = q / 7, j = q - s * 7;
            sum += red[(s * 28 + pg4 * 7 + j) * 33 + sub * 8 + e];
        }
        const int row = 1 + py * 16 + p;
        sum += bm[e] + pe[row * 8 + e];
        xws[((size_t)n * 257 + row) * 8 + e] = sum;   // coalesced 128 floats
    }
}

// ---------------------------------------------------------------------------
// Kernel 2 (v2, verbatim from round 7 — measured-passing): one block per
// image, 576 threads. P1 fused LN1+QKV; P2 attention 2 rows/thread.
// ---------------------------------------------------------------------------
__global__ __launch_bounds__(576) void k_transformer(
    const float* __restrict__ xws, const int* __restrict__ labels,
    const float* __restrict__ cls_table, const float* __restrict__ pe,
    const float* __restrict__ ln1_g, const float* __restrict__ ln1_b,
    const float* __restrict__ Wq, const float* __restrict__ bq,
    const float* __restrict__ Wk, const float* __restrict__ bk,
    const float* __restrict__ Wv, const float* __restrict__ bv,
    const float* __restrict__ ln2_g, const float* __restrict__ ln2_b,
    const float* __restrict__ W1, const float* __restrict__ b1,
    const float* __restrict__ W2, const float* __restrict__ b2,
    const float* __restrict__ Wf, const float* __restrict__ bf,
    float* __restrict__ out)
{
    __shared__ __align__(16) float xb[257 * 9];
    __shared__ __align__(16) float hb[257 * 9];
    __shared__ __align__(16) float qb[2 * 257 * 4];
    __shared__ __align__(16) float kb[2 * 257 * 4];
    __shared__ __align__(16) float vb[2 * 257 * 4];
    __shared__ float wqs[64], wks[64], wvs[64];
    __shared__ float bqs[16], bks[16], bvs[16];
    __shared__ float w1s[512], b1s[64], w2s[512], b2s[16];

    const int t = threadIdx.x;
    const int n = blockIdx.x;
    const float* xn = xws + (size_t)n * 2056;

    for (int i = t; i < 64; i += 576) { wqs[i] = Wq[i]; wks[i] = Wk[i]; wvs[i] = Wv[i]; b1s[i] = b1[i]; }
    for (int i = t; i < 16; i += 576) { bqs[i] = bq[i]; bks[i] = bk[i]; bvs[i] = bv[i]; b2s[i] = b2[i]; }
    for (int i = t; i < 512; i += 576) { w1s[i] = W1[i]; w2s[i] = W2[i]; }

    if (t < 512) {
        float4 v = reinterpret_cast<const float4*>(xn)[t + 2];
        const int s = (t + 2) >> 1;
        const int e0 = (t & 1) ? 4 : 0;
        float* d = xb + s * 9 + e0;
        d[0] = v.x; d[1] = v.y; d[2] = v.z; d[3] = v.w;
    } else if (t < 520) {
        const int e = t - 512;
        xb[e] = cls_table[labels[n] * 8 + e] + pe[e];
    }
    __syncthreads();

    const float SC = 0.72134752044f;   // (1/sqrt(DH)=0.5) * log2(e)

    for (int l = 0; l < 2; ++l) {
        if (t < 257) {
            float v0[8]; float m = 0.f;
            #pragma unroll
            for (int e = 0; e < 8; ++e) { v0[e] = xb[t * 9 + e]; m += v0[e]; }
            m *= 0.125f;
            float var = 0.f;
            #pragma unroll
            for (int e = 0; e < 8; ++e) { float d = v0[e] - m; var += d * d; }
            var *= 0.125f;
            const float rs = rsqrtf(var + 1e-5f);
            const float* g = ln1_g + l * 8; const float* bb = ln1_b + l * 8;
            float ln[8];
            #pragma unroll
            for (int e = 0; e < 8; ++e) ln[e] = (v0[e] - m) * rs * g[e] + bb[e];

            #pragma unroll
            for (int h = 0; h < 2; ++h) {
                const int wb_ = (l * 2 + h);
                const float* wq = wqs + wb_ * 16; const float* bq_ = bqs + wb_ * 4;
                const float* wk = wks + wb_ * 16; const float* bk_ = bks + wb_ * 4;
                const float* wv = wvs + wb_ * 16; const float* bv_ = bvs + wb_ * 4;
                float qq[4], kk[4], vv[4];
                #pragma unroll
                for (int e = 0; e < 4; ++e) { qq[e] = bq_[e]; kk[e] = bk_[e]; vv[e] = bv_[e]; }
                #pragma unroll
                for (int d = 0; d < 4; ++d) {
                    const float hd = ln[h * 4 + d];
                    #pragma unroll
                    for (int e = 0; e < 4; ++e) {
                        qq[e] += hd * wq[d * 4 + e];
                        kk[e] += hd * wk[d * 4 + e];
                        vv[e] += hd * wv[d * 4 + e];
                    }
                }
                const int ri = (h * 257 + t) * 4;
                *reinterpret_cast<float4*>(qb + ri) =
                    make_float4(qq[0] * SC, qq[1] * SC, qq[2] * SC, qq[3] * SC);
                *reinterpret_cast<float4*>(kb + ri) = make_float4(kk[0], kk[1], kk[2], kk[3]);
                *reinterpret_cast<float4*>(vb + ri) = make_float4(vv[0], vv[1], vv[2], vv[3]);
            }
        }
        __syncthreads();

        if (t < 258) {
            const int h = (t >= 129) ? 1 : 0;
            const int j = t - 129 * h;
            const int s0 = j;
            const int s1 = j + 129;
            const bool has2 = (j < 128);
            const float4* qp = reinterpret_cast<const float4*>(qb) + h * 257;
            const float4* kp = reinterpret_cast<const float4*>(kb) + h * 257;
            const float4* vp = reinterpret_cast<const float4*>(vb) + h * 257;
            const float4 q0 = qp[s0];
            const float4 q1 = qp[has2 ? s1 : s0];

            float l0 = 0.f, o00 = 0.f, o01 = 0.f, o02 = 0.f, o03 = 0.f;
            float l1 = 0.f, o10 = 0.f, o11 = 0.f, o12 = 0.f, o13 = 0.f;
            #pragma unroll 4
            for (int tt = 0; tt < 257; ++tt) {
                const float4 kk = kp[tt];
                const float4 vv = vp[tt];
                const float d0 = q0.x*kk.x + q0.y*kk.y + q0.z*kk.z + q0.w*kk.w;
                const float d1 = q1.x*kk.x + q1.y*kk.y + q1.z*kk.z + q1.w*kk.w;
                const float p0 = exp2f(d0);
                const float p1 = exp2f(d1);
                l0 += p0; l1 += p1;
                o00 += p0*vv.x; o01 += p0*vv.y; o02 += p0*vv.z; o03 += p0*vv.w;
                o10 += p1*vv.x; o11 += p1*vv.y; o12 += p1*vv.z; o13 += p1*vv.w;
            }
            const float i0 = 1.0f / l0;
            float* xr0 = xb + s0 * 9 + h * 4;
            xr0[0] += o00*i0; xr0[1] += o01*i0; xr0[2] += o02*i0; xr0[3] += o03*i0;
            if (has2) {
                const float i1 = 1.0f / l1;
                float* xr1 = xb + s1 * 9 + h * 4;
                xr1[0] += o10*i1; xr1[1] += o11*i1; xr1[2] += o12*i1; xr1[3] += o13*i1;
            }
        }
        __syncthreads();

        if (t < 257) {
            float v0[8]; float m = 0.f;
            #pragma unroll
            for (int e = 0; e < 8; ++e) { v0[e] = xb[t * 9 + e]; m += v0[e]; }
            m *= 0.125f;
            float var = 0.f;
            #pragma unroll
            for (int e = 0; e < 8; ++e) { float d = v0[e] - m; var += d * d; }
            var *= 0.125f;
            const float rs = rsqrtf(var + 1e-5f);
            const float* g = ln2_g + l * 8; const float* bb = ln2_b + l * 8;
            #pragma unroll
            for (int e = 0; e < 8; ++e) hb[t * 9 + e] = (v0[e] - m) * rs * g[e] + bb[e];
        }
        __syncthreads();

        if (t < 257) {
            float hv[8];
            #pragma unroll
            for (int e = 0; e < 8; ++e) hv[e] = hb[t * 9 + e];
            float a8[8] = {0.f, 0.f, 0.f, 0.f, 0.f, 0.f, 0.f, 0.f};
            const float* w1 = w1s + l * 256; const float* bb1 = b1s + l * 32;
            const float* w2 = w2s + l * 256; const float* bb2 = b2s + l * 8;
            for (int u = 0; u < 32; ++u) {
                float a = bb1[u];
                #pragma unroll
                for (int e = 0; e < 8; ++e) a += hv[e] * w1[e * 32 + u];
                const float gl = 0.5f * a * (1.0f + erff(a * 0.70710678f));
                #pragma unroll
                for (int e = 0; e < 8; ++e) a8[e] += gl * w2[u * 8 + e];
            }
            #pragma unroll
            for (int e = 0; e < 8; ++e) xb[t * 9 + e] += a8[e] + bb2[e];
        }
        __syncthreads();
    }

    if (t < 10) {
        float a = bf[t];
        #pragma unroll
        for (int e = 0; e < 8; ++e) a += xb[e] * Wf[e * 10 + t];
        out[(size_t)n * 10 + t] = a;
    }
}

extern "C" void kernel_launch(void* const* d_in, const int* in_sizes, int n_in,
                              void* d_out, int out_size, void* d_ws, size_t ws_size,
                              hipStream_t stream) {
    const float* img    = (const float*)d_in[0];
    const int*   labels = (const int*)  d_in[1];
    const float* Wm     = (const float*)d_in[2];
    const float* bm     = (const float*)d_in[3];
    const float* cls    = (const float*)d_in[4];
    const float* pe     = (const float*)d_in[5];
    const float* ln1_g  = (const float*)d_in[6];
    const float* ln1_b  = (const float*)d_in[7];
    const float* Wq     = (const float*)d_in[8];
    const float* bq     = (const float*)d_in[9];
    const float* Wk     = (const float*)d_in[10];
    const float* bk     = (const float*)d_in[11];
    const float* Wv     = (const float*)d_in[12];
    const float* bv     = (const float*)d_in[13];
    const float* ln2_g  = (const float*)d_in[14];
    const float* ln2_b  = (const float*)d_in[15];
    const float* W1     = (const float*)d_in[16];
    const float* b1     = (const float*)d_in[17];
    const float* W2     = (const float*)d_in[18];
    const float* b2     = (const float*)d_in[19];
    const float* Wf     = (const float*)d_in[20];
    const float* bf     = (const float*)d_in[21];
    float* out = (float*)d_out;
    float* xws = (float*)d_ws;                     // 512*257*8 floats = 4.2 MB

    const int n = in_sizes[0] / N_IMG_D;           // 512 images
    k_patch_embed<<<n * 16, 256, 0, stream>>>(img, Wm, bm, pe, xws);
    k_transformer<<<n, 576, 0, stream>>>(xws, labels, cls, pe, ln1_g, ln1_b,
        Wq, bq, Wk, bk, Wv, bv, ln2_g, ln2_b, W1, b1, W2, b2, Wf, bf, out);
}